// Round 6
// baseline (243.020 us; speedup 1.0000x reference)
//
#include <hip/hip_runtime.h>
#include <hip/hip_bf16.h>

typedef __attribute__((ext_vector_type(4))) float f32x4;
typedef __attribute__((ext_vector_type(8))) short s16x8;

constexpr int NN   = 8192;
constexpr int KIN  = 512;
constexpr int KOUT = 128;

constexpr int JCHUNK = 8;
constexpr int JLEN   = NN / JCHUNK;   // 1024
constexpr int SG     = 32;            // stage width (cols)
constexpr int NS     = JLEN / SG;     // 32 stages
// LDS: buf k at k*16384 = {M 8KB | hT 8KB}; ring-3 = 48KB total
constexpr int BUFSTRIDE = 16384;
constexpr int H_OFF = 8192;

__device__ __forceinline__ ushort f2bf(float x) {
    union { float f; unsigned u; } v; v.f = x;
    unsigned r = (v.u + 0x7fffu + ((v.u >> 16) & 1u)) >> 16;
    return (ushort)r;
}

__device__ __forceinline__ void gload_lds16(const void* g, void* l) {
    __builtin_amdgcn_global_load_lds((const __attribute__((address_space(1))) void*)g,
                                     (__attribute__((address_space(3))) void*)l, 16, 0, 0);
}

// ---------------- kZero: zero o_acc (4 MB) fast ----------------
__global__ __launch_bounds__(256) void kZero(float* __restrict__ p) {
    const int idx = blockIdx.x * 256 + threadIdx.x;
    *(f32x4*)(p + (size_t)idx * 4) = (f32x4){0.f, 0.f, 0.f, 0.f};
}

// ---------------- kPrep: adj (f32 0/1) -> bitmask, 1 u32 per 32 cols ----------------
__global__ __launch_bounds__(256) void kPrep(const float* __restrict__ adjm,
                                             unsigned* __restrict__ bm) {
    const int wi = blockIdx.x * 256 + threadIdx.x;    // word index, 2,097,152 total
    const float* p = adjm + (size_t)wi * 32;
    unsigned b = 0;
#pragma unroll
    for (int q = 0; q < 8; ++q) {
        f32x4 v = *(const f32x4*)(p + q * 4);
#pragma unroll
        for (int e = 0; e < 4; ++e) b |= (v[e] > 0.f ? 1u : 0u) << (q * 4 + e);
    }
    bm[wi] = b;
}

// ---------------- Kernel A: h = input @ W ; hT(bf16), s, t ----------------
__global__ __launch_bounds__(256) void kA(const float* __restrict__ inp,
                                          const float* __restrict__ W,
                                          const float* __restrict__ a_s,
                                          const float* __restrict__ a_n,
                                          ushort* __restrict__ hT,
                                          float* __restrict__ s_out,
                                          float* __restrict__ t_out) {
    __shared__ float smem[16 * 512];
    const int t = threadIdx.x;
    const int rbase = blockIdx.x * 16;

#pragma unroll
    for (int it = 0; it < 8; ++it) {
        int idx = it * 256 + t;
        int r = idx >> 7;
        int c4 = (idx & 127) << 2;
        *(f32x4*)(&smem[r * 512 + c4]) =
            *(const f32x4*)(inp + (size_t)(rbase + r) * KIN + c4);
    }
    __syncthreads();

    const int c0 = (t & 31) * 4;
    const int rg = (t >> 5) * 2;
    float acc[2][4] = {};
#pragma unroll 4
    for (int k = 0; k < KIN; ++k) {
        f32x4 w4 = *(const f32x4*)(W + (size_t)k * KOUT + c0);
        float a0 = smem[(rg + 0) * 512 + k];
        float a1 = smem[(rg + 1) * 512 + k];
#pragma unroll
        for (int cc = 0; cc < 4; ++cc) {
            acc[0][cc] += a0 * w4[cc];
            acc[1][cc] += a1 * w4[cc];
        }
    }
    __syncthreads();

    float* h_lds = smem;                        // [16][128]
#pragma unroll
    for (int rr = 0; rr < 2; ++rr) {
        f32x4 v = {acc[rr][0], acc[rr][1], acc[rr][2], acc[rr][3]};
        *(f32x4*)(&h_lds[(rg + rr) * 128 + c0]) = v;
    }
    __syncthreads();

    {
        const int col = t >> 1;
        const int r0 = (t & 1) * 8;
        ushort tmp[8];
#pragma unroll
        for (int rr = 0; rr < 8; ++rr) tmp[rr] = f2bf(h_lds[(r0 + rr) * 128 + col]);
        *(f32x4*)(hT + (size_t)col * NN + rbase + r0) = *(f32x4*)&tmp[0];
    }

    {
        const int w = t >> 6, lane = t & 63;
        float as1 = a_s[lane], as2 = a_s[64 + lane];
        float an1 = a_n[lane], an2 = a_n[64 + lane];
#pragma unroll
        for (int rr = 0; rr < 4; ++rr) {
            int row = w * 4 + rr;
            float h1 = h_lds[row * 128 + lane];
            float h2 = h_lds[row * 128 + 64 + lane];
            float ps = h1 * as1 + h2 * as2;
            float pt = h1 * an1 + h2 * an2;
#pragma unroll
            for (int off = 32; off; off >>= 1) {
                ps += __shfl_xor(ps, off);
                pt += __shfl_xor(pt, off);
            }
            if (lane == 0) {
                s_out[rbase + row] = ps;
                t_out[rbase + row] = pt;
            }
        }
    }
}

// ---------------- Kernel B v5: M+hT DMA ring-3, bits/t reg-prefetch, atomics out ----------------
// grid 1024: rb = bid>>3 (64 rows), jc = bid&7 (1024 cols). 4 waves; wave w rows w*16..+15.
// Per wave per stage: 4 DMA (M x2, hT x2) + 3 regloads (bits u32, t f32x4 x2).
// Iter order: wait vmcnt(4) | barrier | regload(s+1) | ISSUE DMA(s+2) | compute(s).
__global__ __launch_bounds__(256, 3) void kB(const float* __restrict__ Mmat,
                                             const unsigned* __restrict__ bm,
                                             const ushort* __restrict__ hT,
                                             const float* __restrict__ s_in,
                                             const float* __restrict__ t_in,
                                             float* __restrict__ o_acc,
                                             float* __restrict__ l_part) {
    __shared__ f32x4 LDSQ[49152 / 16];
    char* LDS = (char*)LDSQ;

    const int tid = threadIdx.x;
    const int w = tid >> 6;
    const int l = tid & 63;
    const int lrow = l & 15;             // MFMA A-row this lane owns
    const int kgrp = l >> 4;             // MFMA k-group (8 cols each)
    const int rb = blockIdx.x >> 3;
    const int jc = blockIdx.x & 7;
    const int j0 = jc * JLEN;
    const int i = rb * 64 + w * 16 + lrow;

    const float si = s_in[i];

    // ---- DMA source pointers (pre-swizzled global source, linear LDS dst) ----
    const int rl8 = l >> 3, c8 = l & 7;
    const int csMA = c8 ^ rl8;
    const float* gM0 = Mmat + (size_t)(rb * 64 + w * 16 + rl8) * NN + j0 + csMA * 4;
    const float* gM1 = gM0 + (size_t)8 * NN;
    const int rl4 = l >> 2, c4 = l & 3;
    const int csH = c4 ^ (rl8 & 3);
    const ushort* gH0 = hT + (size_t)(w * 32 + rl4) * NN + j0 + csH * 8;
    const ushort* gH1 = gH0 + (size_t)16 * NN;

    // LDS dst offsets (wave-uniform)
    const int mdst0 = (w * 16) * 128, mdst1 = (w * 16 + 8) * 128;
    const int hdst0 = H_OFF + (w * 32) * 64, hdst1 = H_OFF + (w * 32 + 16) * 64;

    // per-thread constant LDS read offsets (swizzled)
    const int Cm0 = (w * 16 + lrow) * 128 + (((kgrp * 2 + 0) ^ (lrow & 7)) << 4);
    const int Cm1 = (w * 16 + lrow) * 128 + (((kgrp * 2 + 1) ^ (lrow & 7)) << 4);
    const int Ch  = H_OFF + lrow * 64 + ((kgrp ^ ((lrow >> 1) & 3)) << 4);

    // regload sources for bits / t
    const unsigned* bwp = bm + (size_t)i * 256 + (j0 >> 5);
    const float* tp = t_in + j0 + kgrp * 8;

    f32x4 acc[8];
#pragma unroll
    for (int ct = 0; ct < 8; ++ct) acc[ct] = (f32x4){0.f, 0.f, 0.f, 0.f};
    float lsum = 0.f;

#define ISSUE(BB)                                                  \
    gload_lds16(gM0, LDS + (BB) + mdst0);                          \
    gload_lds16(gM1, LDS + (BB) + mdst1);                          \
    gload_lds16(gH0, LDS + (BB) + hdst0);                          \
    gload_lds16(gH1, LDS + (BB) + hdst1);

#define ADV() gM0 += SG; gM1 += SG; gH0 += SG; gH1 += SG;

    // prologue: DMA s0, regload s0, DMA s1  (ordering matters for vmcnt)
    ISSUE(0)
    ADV()
    unsigned mk = bwp[0];
    f32x4 ta0 = *(const f32x4*)(tp);
    f32x4 ta1 = *(const f32x4*)(tp + 4);
    ISSUE(BUFSTRIDE)
    ADV()

    unsigned b0 = 0, b1 = BUFSTRIDE, b2 = 2 * BUFSTRIDE;

#pragma unroll 1
    for (int s = 0; s < NS; ++s) {
        asm volatile("s_waitcnt vmcnt(4)" ::: "memory");   // stage-s DMA (+its regloads) landed
        __builtin_amdgcn_s_barrier();                      // all waves' stage-s in LDS
        asm volatile("" ::: "memory");

        // regload stage s+1 (BEFORE next DMA issue, so vmcnt(4) math stays exact)
        const int sn = (s + 1 < NS) ? (s + 1) : s;
        unsigned mk_n = bwp[sn];
        f32x4 tn0 = *(const f32x4*)(tp + sn * SG);
        f32x4 tn1 = *(const f32x4*)(tp + sn * SG + 4);

        ISSUE(b2)                                          // DMA stage s+2 (dummy re-issue at tail)
        if (s + 3 < NS) { ADV() }

        // ---- compute stage s from buf b0 + regs (mk, ta0, ta1) ----
        {
            f32x4 mv0 = *(const f32x4*)(LDS + b0 + Cm0);
            f32x4 mv1 = *(const f32x4*)(LDS + b0 + Cm1);

            s16x8 af;
#pragma unroll
            for (int e = 0; e < 4; ++e) {
                float x = (si + ta0[e]) * mv0[e];
                x = fmaxf(x, 0.2f * x);
                float p = __expf(x);
                p = ((mk >> (kgrp * 8 + e)) & 1u) ? p : 0.f;
                lsum += p;
                af[e] = (short)f2bf(p);
            }
#pragma unroll
            for (int e = 0; e < 4; ++e) {
                float x = (si + ta1[e]) * mv1[e];
                x = fmaxf(x, 0.2f * x);
                float p = __expf(x);
                p = ((mk >> (kgrp * 8 + 4 + e)) & 1u) ? p : 0.f;
                lsum += p;
                af[4 + e] = (short)f2bf(p);
            }

            const char* hb = LDS + b0 + Ch;
#pragma unroll
            for (int ct = 0; ct < 8; ++ct) {
                s16x8 bf = *(const s16x8*)(hb + ct * 1024);
                acc[ct] = __builtin_amdgcn_mfma_f32_16x16x32_bf16(af, bf, acc[ct], 0, 0, 0);
            }
        }

        mk = mk_n; ta0 = tn0; ta1 = tn1;                   // rotate reg prefetch
        unsigned bt = b0; b0 = b1; b1 = b2; b2 = bt;       // rotate ring
    }
#undef ISSUE
#undef ADV

    // denominator partials
    lsum += __shfl_xor(lsum, 16);
    lsum += __shfl_xor(lsum, 32);
    if (l < 16) l_part[(size_t)jc * NN + i] = lsum;

    // o accumulation via atomics (D layout: row=(lane>>4)*4+reg, col=lane&15)
#pragma unroll
    for (int ct = 0; ct < 8; ++ct) {
#pragma unroll
        for (int r = 0; r < 4; ++r) {
            int gi = rb * 64 + w * 16 + kgrp * 4 + r;
            int col = ct * 16 + lrow;
            atomicAdd(&o_acc[(size_t)gi * KOUT + col], acc[ct][r]);
        }
    }
}

// ---------------- Kernel C: divide, ELU ----------------
__global__ __launch_bounds__(256) void kC(const float* __restrict__ o_acc,
                                          const float* __restrict__ l_part,
                                          float* __restrict__ out) {
    const int idx = blockIdx.x * 256 + threadIdx.x;
    const int i = idx >> 7;
    float lsum = 0.f;
#pragma unroll
    for (int p = 0; p < JCHUNK; ++p) lsum += l_part[(size_t)p * NN + i];
    float v = o_acc[idx] / lsum;
    out[idx] = v > 0.f ? v : (__expf(v) - 1.f);
}

extern "C" void kernel_launch(void* const* d_in, const int* in_sizes, int n_in,
                              void* d_out, int out_size, void* d_ws, size_t ws_size,
                              hipStream_t stream) {
    const float* inp = (const float*)d_in[0];
    const float* adj = (const float*)d_in[1];
    const float* Mm  = (const float*)d_in[2];
    const float* W   = (const float*)d_in[3];
    const float* a_s = (const float*)d_in[4];
    const float* a_n = (const float*)d_in[5];
    float* out = (float*)d_out;

    char* ws = (char*)d_ws;
    ushort*   hT    = (ushort*)(ws + 0);             //  2 MB   [128][8192] bf16
    float*    s_buf = (float*)(ws + 2097152);        //  32 KB
    float*    t_buf = (float*)(ws + 2129920);        //  32 KB
    float*    l_prt = (float*)(ws + 2162688);        //  256 KB [8][8192]
    float*    o_acc = (float*)(ws + 4194304);        //  4 MB   [8192][128]
    unsigned* bmask = (unsigned*)(ws + 8388608);     //  8 MB   [8192][256] u32

    hipLaunchKernelGGL(kZero, dim3(NN * KOUT / 4 / 256), dim3(256), 0, stream, o_acc);
    hipLaunchKernelGGL(kPrep, dim3(NN * NN / 32 / 256), dim3(256), 0, stream, adj, bmask);
    hipLaunchKernelGGL(kA, dim3(512), dim3(256), 0, stream, inp, W, a_s, a_n, hT, s_buf, t_buf);
    hipLaunchKernelGGL(kB, dim3(128 * JCHUNK), dim3(256), 0, stream, Mm, bmask, hT, s_buf, t_buf, o_acc, l_prt);
    hipLaunchKernelGGL(kC, dim3(4096), dim3(256), 0, stream, o_acc, l_prt, out);
}

// Round 7
// 236.719 us; speedup vs baseline: 1.0266x; 1.0266x over previous
//
#include <hip/hip_runtime.h>
#include <hip/hip_bf16.h>

typedef __attribute__((ext_vector_type(4))) float f32x4;
typedef __attribute__((ext_vector_type(8))) short s16x8;

constexpr int NN   = 8192;
constexpr int KIN  = 512;
constexpr int KOUT = 128;

constexpr int JCHUNK = 8;
constexpr int JLEN   = NN / JCHUNK;   // 1024
constexpr int SG     = 32;            // stage width (cols)
constexpr int NS     = JLEN / SG;     // 32 stages
constexpr int HBUF   = 8192;          // bytes per hT stage buffer (128 rows x 32 cols bf16)

__device__ __forceinline__ ushort f2bf(float x) {
    union { float f; unsigned u; } v; v.f = x;
    unsigned r = (v.u + 0x7fffu + ((v.u >> 16) & 1u)) >> 16;
    return (ushort)r;
}

__device__ __forceinline__ void gload_lds16(const void* g, void* l) {
    __builtin_amdgcn_global_load_lds((const __attribute__((address_space(1))) void*)g,
                                     (__attribute__((address_space(3))) void*)l, 16, 0, 0);
}

// ---------------- kZero: zero o_acc (4 MB) ----------------
__global__ __launch_bounds__(256) void kZero(float* __restrict__ p) {
    const int idx = blockIdx.x * 256 + threadIdx.x;
    *(f32x4*)(p + (size_t)idx * 4) = (f32x4){0.f, 0.f, 0.f, 0.f};
}

// ---------------- kPrep: adj (f32 0/1) -> bitmask ----------------
__global__ __launch_bounds__(256) void kPrep(const float* __restrict__ adjm,
                                             unsigned* __restrict__ bm) {
    const int wi = blockIdx.x * 256 + threadIdx.x;
    const float* p = adjm + (size_t)wi * 32;
    unsigned b = 0;
#pragma unroll
    for (int q = 0; q < 8; ++q) {
        f32x4 v = *(const f32x4*)(p + q * 4);
#pragma unroll
        for (int e = 0; e < 4; ++e) b |= (v[e] > 0.f ? 1u : 0u) << (q * 4 + e);
    }
    bm[wi] = b;
}

// ---------------- Kernel A: h = input @ W ; hT(bf16), s, t ----------------
__global__ __launch_bounds__(256) void kA(const float* __restrict__ inp,
                                          const float* __restrict__ W,
                                          const float* __restrict__ a_s,
                                          const float* __restrict__ a_n,
                                          ushort* __restrict__ hT,
                                          float* __restrict__ s_out,
                                          float* __restrict__ t_out) {
    __shared__ float smem[16 * 512];
    const int t = threadIdx.x;
    const int rbase = blockIdx.x * 16;

#pragma unroll
    for (int it = 0; it < 8; ++it) {
        int idx = it * 256 + t;
        int r = idx >> 7;
        int c4 = (idx & 127) << 2;
        *(f32x4*)(&smem[r * 512 + c4]) =
            *(const f32x4*)(inp + (size_t)(rbase + r) * KIN + c4);
    }
    __syncthreads();

    const int c0 = (t & 31) * 4;
    const int rg = (t >> 5) * 2;
    float acc[2][4] = {};
#pragma unroll 4
    for (int k = 0; k < KIN; ++k) {
        f32x4 w4 = *(const f32x4*)(W + (size_t)k * KOUT + c0);
        float a0 = smem[(rg + 0) * 512 + k];
        float a1 = smem[(rg + 1) * 512 + k];
#pragma unroll
        for (int cc = 0; cc < 4; ++cc) {
            acc[0][cc] += a0 * w4[cc];
            acc[1][cc] += a1 * w4[cc];
        }
    }
    __syncthreads();

    float* h_lds = smem;                        // [16][128]
#pragma unroll
    for (int rr = 0; rr < 2; ++rr) {
        f32x4 v = {acc[rr][0], acc[rr][1], acc[rr][2], acc[rr][3]};
        *(f32x4*)(&h_lds[(rg + rr) * 128 + c0]) = v;
    }
    __syncthreads();

    {
        const int col = t >> 1;
        const int r0 = (t & 1) * 8;
        ushort tmp[8];
#pragma unroll
        for (int rr = 0; rr < 8; ++rr) tmp[rr] = f2bf(h_lds[(r0 + rr) * 128 + col]);
        *(f32x4*)(hT + (size_t)col * NN + rbase + r0) = *(f32x4*)&tmp[0];
    }

    {
        const int w = t >> 6, lane = t & 63;
        float as1 = a_s[lane], as2 = a_s[64 + lane];
        float an1 = a_n[lane], an2 = a_n[64 + lane];
#pragma unroll
        for (int rr = 0; rr < 4; ++rr) {
            int row = w * 4 + rr;
            float h1 = h_lds[row * 128 + lane];
            float h2 = h_lds[row * 128 + 64 + lane];
            float ps = h1 * as1 + h2 * as2;
            float pt = h1 * an1 + h2 * an2;
#pragma unroll
            for (int off = 32; off; off >>= 1) {
                ps += __shfl_xor(ps, off);
                pt += __shfl_xor(pt, off);
            }
            if (lane == 0) {
                s_out[rbase + row] = ps;
                t_out[rbase + row] = pt;
            }
        }
    }
}

// ---------------- Kernel B v6 ----------------
// grid 1024: rb = bid>>3 (64 rows), jc = bid&7 (1024 cols). 4 waves, wave w rows w*16..+15.
// M/bm/t: per-lane register loads in A-fragment layout, unroll-2 ping-pong, distance-2.
// hT: global_load_lds ring-3 (24 KB), distance-2. Invariant: 7 vmem per stage -> vmcnt(7).
__global__ __launch_bounds__(256, 4) void kB(const float* __restrict__ Mmat,
                                             const unsigned* __restrict__ bm,
                                             const ushort* __restrict__ hT,
                                             const float* __restrict__ s_in,
                                             const float* __restrict__ t_in,
                                             float* __restrict__ o_acc,
                                             float* __restrict__ l_part) {
    __shared__ f32x4 LDSQ[3 * HBUF / 16];
    char* LDS = (char*)LDSQ;

    const int tid = threadIdx.x;
    const int w = tid >> 6;
    const int l = tid & 63;
    const int lrow = l & 15;             // MFMA A-row this lane owns
    const int kgrp = l >> 4;             // MFMA k-group (8 cols each)
    const int rb = blockIdx.x >> 3;
    const int jc = blockIdx.x & 7;
    const int j0 = jc * JLEN;
    const int i = rb * 64 + w * 16 + lrow;

    const float si = s_in[i];

    // per-lane fragment-layout sources
    const float*    Mp = Mmat + (size_t)i * NN + j0 + kgrp * 8;
    const unsigned* bp = bm + (size_t)i * 256 + (j0 >> 5);
    const float*    tp = t_in + j0 + kgrp * 8;

    // hT DMA source (pre-swizzled global, linear LDS dst) — validated path from R4-R6
    const int rl8 = l >> 3;
    const int rl4 = l >> 2, c4i = l & 3;
    const int csH = c4i ^ (rl8 & 3);
    const ushort* gH0 = hT + (size_t)(w * 32 + rl4) * NN + j0 + csH * 8;
    const ushort* gH1 = gH0 + (size_t)16 * NN;
    const int hdst0 = (w * 32) * 64;
    const int hdst1 = (w * 32 + 16) * 64;
    const int Ch = lrow * 64 + ((kgrp ^ ((lrow >> 1) & 3)) << 4);

    f32x4 acc[8];
#pragma unroll
    for (int ct = 0; ct < 8; ++ct) acc[ct] = (f32x4){0.f, 0.f, 0.f, 0.f};
    float lsum = 0.f;

#define DMA_H(HB, SS)                                              \
    gload_lds16(gH0 + (SS) * SG, LDS + (HB) + hdst0);              \
    gload_lds16(gH1 + (SS) * SG, LDS + (HB) + hdst1);

#define LD_RT(MK, T0, T1, SS)                                      \
    MK = bp[(SS)];                                                 \
    T0 = *(const f32x4*)(tp + (SS) * SG);                          \
    T1 = *(const f32x4*)(tp + (SS) * SG + 4);

#define LD_M(M0, M1, SS)                                           \
    M0 = *(const f32x4*)(Mp + (SS) * SG);                          \
    M1 = *(const f32x4*)(Mp + (SS) * SG + 4);

#define COMPUTE(HB, MK, T0, T1, M0, M1)                                          \
    {                                                                            \
        s16x8 af;                                                                \
        _Pragma("unroll")                                                        \
        for (int e = 0; e < 4; ++e) {                                            \
            float x = (si + (T0)[e]) * (M0)[e];                                  \
            x = fmaxf(x, 0.2f * x);                                              \
            float p = __expf(x);                                                 \
            p = (((MK) >> (kgrp * 8 + e)) & 1u) ? p : 0.f;                       \
            lsum += p;                                                           \
            af[e] = (short)f2bf(p);                                              \
        }                                                                        \
        _Pragma("unroll")                                                        \
        for (int e = 0; e < 4; ++e) {                                            \
            float x = (si + (T1)[e]) * (M1)[e];                                  \
            x = fmaxf(x, 0.2f * x);                                              \
            float p = __expf(x);                                                 \
            p = (((MK) >> (kgrp * 8 + 4 + e)) & 1u) ? p : 0.f;                   \
            lsum += p;                                                           \
            af[4 + e] = (short)f2bf(p);                                          \
        }                                                                        \
        const char* hb = LDS + (HB) + Ch;                                        \
        _Pragma("unroll")                                                        \
        for (int ct = 0; ct < 8; ++ct) {                                         \
            s16x8 bf = *(const s16x8*)(hb + ct * 1024);                          \
            acc[ct] = __builtin_amdgcn_mfma_f32_16x16x32_bf16(af, bf, acc[ct], 0, 0, 0); \
        }                                                                        \
    }

    // ping-pong register sets
    unsigned mkA, mkB;
    f32x4 tA0, tA1, tB0, tB1, mA0, mA1, mB0, mB1;
    int hA = 0, hB = HBUF, hC = 2 * HBUF;

    // prologue: [DMA(0), rt(0), M(0)] [DMA(1), rt(1), M(1)] -> 14 outstanding
    DMA_H(hA, 0)
    LD_RT(mkA, tA0, tA1, 0)
    LD_M(mA0, mA1, 0)
    DMA_H(hB, 1)
    LD_RT(mkB, tB0, tB1, 1)
    LD_M(mB0, mB1, 1)

#pragma unroll 1
    for (int s = 0; s < NS; s += 2) {
        const int s2 = (s + 2 < NS) ? s + 2 : NS - 1;   // clamped prefetch (dup of last stage)
        const int s3 = (s + 3 < NS) ? s + 3 : NS - 1;

        // ---- even sub-iter: stage s (set A, buf hA) ----
        asm volatile("s_waitcnt vmcnt(7)" ::: "memory");  // DMA(s), rt(s), M(s) landed
        __builtin_amdgcn_s_barrier();
        asm volatile("" ::: "memory");
        DMA_H(hC, s2)
        COMPUTE(hA, mkA, tA0, tA1, mA0, mA1)
        LD_RT(mkA, tA0, tA1, s2)
        LD_M(mA0, mA1, s2)

        // ---- odd sub-iter: stage s+1 (set B, buf hB) ----
        asm volatile("s_waitcnt vmcnt(7)" ::: "memory");  // DMA(s+1), rt(s+1), M(s+1) landed
        __builtin_amdgcn_s_barrier();
        asm volatile("" ::: "memory");
        DMA_H(hA, s3)
        COMPUTE(hB, mkB, tB0, tB1, mB0, mB1)
        LD_RT(mkB, tB0, tB1, s3)
        LD_M(mB0, mB1, s3)

        // rotate ring: next even reads old hC, next odd reads old hA(rewritten at s3... ring period 3)
        int ht = hA; hA = hC; hC = hB; hB = ht;
    }
#undef DMA_H
#undef LD_RT
#undef LD_M
#undef COMPUTE

    // denominator partials: lanes {l, l^16, l^32, l^48} share row lrow
    lsum += __shfl_xor(lsum, 16);
    lsum += __shfl_xor(lsum, 32);
    if (l < 16) l_part[(size_t)jc * NN + i] = lsum;

    // o accumulation via atomics (D layout: row=(lane>>4)*4+reg, col=lane&15)
#pragma unroll
    for (int ct = 0; ct < 8; ++ct) {
#pragma unroll
        for (int r = 0; r < 4; ++r) {
            int gi = rb * 64 + w * 16 + kgrp * 4 + r;
            int col = ct * 16 + lrow;
            atomicAdd(&o_acc[(size_t)gi * KOUT + col], acc[ct][r]);
        }
    }
}

// ---------------- Kernel C: divide, ELU ----------------
__global__ __launch_bounds__(256) void kC(const float* __restrict__ o_acc,
                                          const float* __restrict__ l_part,
                                          float* __restrict__ out) {
    const int idx = blockIdx.x * 256 + threadIdx.x;
    const int i = idx >> 7;
    float lsum = 0.f;
#pragma unroll
    for (int p = 0; p < JCHUNK; ++p) lsum += l_part[(size_t)p * NN + i];
    float v = o_acc[idx] / lsum;
    out[idx] = v > 0.f ? v : (__expf(v) - 1.f);
}

extern "C" void kernel_launch(void* const* d_in, const int* in_sizes, int n_in,
                              void* d_out, int out_size, void* d_ws, size_t ws_size,
                              hipStream_t stream) {
    const float* inp = (const float*)d_in[0];
    const float* adj = (const float*)d_in[1];
    const float* Mm  = (const float*)d_in[2];
    const float* W   = (const float*)d_in[3];
    const float* a_s = (const float*)d_in[4];
    const float* a_n = (const float*)d_in[5];
    float* out = (float*)d_out;

    char* ws = (char*)d_ws;
    ushort*   hT    = (ushort*)(ws + 0);             //  2 MB   [128][8192] bf16
    float*    s_buf = (float*)(ws + 2097152);        //  32 KB
    float*    t_buf = (float*)(ws + 2129920);        //  32 KB
    float*    l_prt = (float*)(ws + 2162688);        //  256 KB [8][8192]
    float*    o_acc = (float*)(ws + 4194304);        //  4 MB   [8192][128]
    unsigned* bmask = (unsigned*)(ws + 8388608);     //  8 MB   [8192][256] u32

    hipLaunchKernelGGL(kZero, dim3(NN * KOUT / 4 / 256), dim3(256), 0, stream, o_acc);
    hipLaunchKernelGGL(kPrep, dim3(NN * NN / 32 / 256), dim3(256), 0, stream, adj, bmask);
    hipLaunchKernelGGL(kA, dim3(512), dim3(256), 0, stream, inp, W, a_s, a_n, hT, s_buf, t_buf);
    hipLaunchKernelGGL(kB, dim3(128 * JCHUNK), dim3(256), 0, stream, Mm, bmask, hT, s_buf, t_buf, o_acc, l_prt);
    hipLaunchKernelGGL(kC, dim3(4096), dim3(256), 0, stream, o_acc, l_prt, out);
}

// Round 8
// 203.492 us; speedup vs baseline: 1.1942x; 1.1633x over previous
//
#include <hip/hip_runtime.h>
#include <hip/hip_bf16.h>

typedef __attribute__((ext_vector_type(4))) float f32x4;
typedef __attribute__((ext_vector_type(8))) short s16x8;

constexpr int NN   = 8192;
constexpr int KIN  = 512;
constexpr int KOUT = 128;

constexpr int JCHUNK = 4;
constexpr int JLEN   = NN / JCHUNK;   // 2048
constexpr int SG     = 32;            // stage width (cols)
constexpr int NS     = JLEN / SG;     // 64 stages
constexpr int HBUF   = 8192;          // bytes per hT stage buffer (128 rows x 32 cols bf16)

__device__ __forceinline__ ushort f2bf(float x) {
    union { float f; unsigned u; } v; v.f = x;
    unsigned r = (v.u + 0x7fffu + ((v.u >> 16) & 1u)) >> 16;
    return (ushort)r;
}

__device__ __forceinline__ void gload_lds16(const void* g, void* l) {
    __builtin_amdgcn_global_load_lds((const __attribute__((address_space(1))) void*)g,
                                     (__attribute__((address_space(3))) void*)l, 16, 0, 0);
}

// ---------------- Kernel A: h = input @ W ; hT(bf16), s, t ----------------
__global__ __launch_bounds__(256) void kA(const float* __restrict__ inp,
                                          const float* __restrict__ W,
                                          const float* __restrict__ a_s,
                                          const float* __restrict__ a_n,
                                          ushort* __restrict__ hT,
                                          float* __restrict__ s_out,
                                          float* __restrict__ t_out) {
    __shared__ float smem[16 * 512];
    const int t = threadIdx.x;
    const int rbase = blockIdx.x * 16;

#pragma unroll
    for (int it = 0; it < 8; ++it) {
        int idx = it * 256 + t;
        int r = idx >> 7;
        int c4 = (idx & 127) << 2;
        *(f32x4*)(&smem[r * 512 + c4]) =
            *(const f32x4*)(inp + (size_t)(rbase + r) * KIN + c4);
    }
    __syncthreads();

    const int c0 = (t & 31) * 4;
    const int rg = (t >> 5) * 2;
    float acc[2][4] = {};
#pragma unroll 4
    for (int k = 0; k < KIN; ++k) {
        f32x4 w4 = *(const f32x4*)(W + (size_t)k * KOUT + c0);
        float a0 = smem[(rg + 0) * 512 + k];
        float a1 = smem[(rg + 1) * 512 + k];
#pragma unroll
        for (int cc = 0; cc < 4; ++cc) {
            acc[0][cc] += a0 * w4[cc];
            acc[1][cc] += a1 * w4[cc];
        }
    }
    __syncthreads();

    float* h_lds = smem;                        // [16][128]
#pragma unroll
    for (int rr = 0; rr < 2; ++rr) {
        f32x4 v = {acc[rr][0], acc[rr][1], acc[rr][2], acc[rr][3]};
        *(f32x4*)(&h_lds[(rg + rr) * 128 + c0]) = v;
    }
    __syncthreads();

    {
        const int col = t >> 1;
        const int r0 = (t & 1) * 8;
        ushort tmp[8];
#pragma unroll
        for (int rr = 0; rr < 8; ++rr) tmp[rr] = f2bf(h_lds[(r0 + rr) * 128 + col]);
        *(f32x4*)(hT + (size_t)col * NN + rbase + r0) = *(f32x4*)&tmp[0];
    }

    {
        const int w = t >> 6, lane = t & 63;
        float as1 = a_s[lane], as2 = a_s[64 + lane];
        float an1 = a_n[lane], an2 = a_n[64 + lane];
#pragma unroll
        for (int rr = 0; rr < 4; ++rr) {
            int row = w * 4 + rr;
            float h1 = h_lds[row * 128 + lane];
            float h2 = h_lds[row * 128 + 64 + lane];
            float ps = h1 * as1 + h2 * as2;
            float pt = h1 * an1 + h2 * an2;
#pragma unroll
            for (int off = 32; off; off >>= 1) {
                ps += __shfl_xor(ps, off);
                pt += __shfl_xor(pt, off);
            }
            if (lane == 0) {
                s_out[rbase + row] = ps;
                t_out[rbase + row] = pt;
            }
        }
    }
}

// ---------------- Kernel B v7 ----------------
// grid 512: rb = bid>>2 (64 rows), jc = bid&3 (2048 cols). 4 waves, wave w rows w*16..+15.
// M/adj/t: per-lane register loads in A-fragment layout, unroll-2 ping-pong, distance-2.
// hT: global_load_lds ring-3 (24 KB), distance-2.
// Invariant: exactly 8 VMEM issued per stage body -> vmcnt(8) at each stage head.
// launch_bounds (256,2): VGPR cap 256 so the ~150-reg pipeline CANNOT spill.
__global__ __launch_bounds__(256, 2) void kB(const float* __restrict__ Mmat,
                                             const float* __restrict__ adjm,
                                             const ushort* __restrict__ hT,
                                             const float* __restrict__ s_in,
                                             const float* __restrict__ t_in,
                                             float* __restrict__ o_part,
                                             float* __restrict__ l_part) {
    __shared__ f32x4 LDSQ[3 * HBUF / 16];
    char* LDS = (char*)LDSQ;

    const int tid = threadIdx.x;
    const int w = tid >> 6;
    const int l = tid & 63;
    const int lrow = l & 15;             // MFMA A-row this lane owns
    const int kgrp = l >> 4;             // MFMA k-group (8 cols each)
    const int rb = blockIdx.x >> 2;
    const int jc = blockIdx.x & 3;
    const int j0 = jc * JLEN;
    const int i = rb * 64 + w * 16 + lrow;

    const float si = s_in[i];

    // per-lane fragment-layout sources
    const float* Mp = Mmat + (size_t)i * NN + j0 + kgrp * 8;
    const float* Ap = adjm + (size_t)i * NN + j0 + kgrp * 8;
    const float* tp = t_in + j0 + kgrp * 8;

    // hT DMA source (pre-swizzled global, linear LDS dst) — validated path
    const int rl8 = l >> 3;
    const int rl4 = l >> 2, c4i = l & 3;
    const int csH = c4i ^ (rl8 & 3);
    const ushort* gH0 = hT + (size_t)(w * 32 + rl4) * NN + j0 + csH * 8;
    const ushort* gH1 = gH0 + (size_t)16 * NN;
    const int hdst0 = (w * 32) * 64;
    const int hdst1 = (w * 32 + 16) * 64;
    const int Ch = lrow * 64 + ((kgrp ^ ((lrow >> 1) & 3)) << 4);

    f32x4 acc[8];
#pragma unroll
    for (int ct = 0; ct < 8; ++ct) acc[ct] = (f32x4){0.f, 0.f, 0.f, 0.f};
    float lsum = 0.f;

#define DMA_H(HB, SS)                                              \
    gload_lds16(gH0 + (size_t)(SS) * SG, LDS + (HB) + hdst0);      \
    gload_lds16(gH1 + (size_t)(SS) * SG, LDS + (HB) + hdst1);

#define LD_R(M0, M1, A0, A1, T0, T1, SS)                           \
    M0 = *(const f32x4*)(Mp + (SS) * SG);                          \
    M1 = *(const f32x4*)(Mp + (SS) * SG + 4);                      \
    A0 = *(const f32x4*)(Ap + (SS) * SG);                          \
    A1 = *(const f32x4*)(Ap + (SS) * SG + 4);                      \
    T0 = *(const f32x4*)(tp + (SS) * SG);                          \
    T1 = *(const f32x4*)(tp + (SS) * SG + 4);

#define COMPUTE(HB, M0, M1, A0, A1, T0, T1)                                      \
    {                                                                            \
        s16x8 af;                                                                \
        _Pragma("unroll")                                                        \
        for (int e = 0; e < 4; ++e) {                                            \
            float x = (si + (T0)[e]) * (M0)[e];                                  \
            x = fmaxf(x, 0.2f * x);                                              \
            float p = __expf(x) * (A0)[e];          /* adj is exactly 0 or 1 */  \
            lsum += p;                                                           \
            af[e] = (short)f2bf(p);                                              \
        }                                                                        \
        _Pragma("unroll")                                                        \
        for (int e = 0; e < 4; ++e) {                                            \
            float x = (si + (T1)[e]) * (M1)[e];                                  \
            x = fmaxf(x, 0.2f * x);                                              \
            float p = __expf(x) * (A1)[e];                                       \
            lsum += p;                                                           \
            af[4 + e] = (short)f2bf(p);                                          \
        }                                                                        \
        const char* hb = LDS + (HB) + Ch;                                        \
        _Pragma("unroll")                                                        \
        for (int ct = 0; ct < 8; ++ct) {                                         \
            s16x8 bf = *(const s16x8*)(hb + ct * 1024);                          \
            acc[ct] = __builtin_amdgcn_mfma_f32_16x16x32_bf16(af, bf, acc[ct], 0, 0, 0); \
        }                                                                        \
    }

    // ping-pong register sets
    f32x4 mA0, mA1, aA0, aA1, tA0, tA1;
    f32x4 mB0, mB1, aB0, aB1, tB0, tB1;
    int hA = 0, hB = HBUF, hC = 2 * HBUF;

    // prologue: group(0) then group(1) -> 16 outstanding
    DMA_H(hA, 0)
    LD_R(mA0, mA1, aA0, aA1, tA0, tA1, 0)
    DMA_H(hB, 1)
    LD_R(mB0, mB1, aB0, aB1, tB0, tB1, 1)

#pragma unroll 1
    for (int s = 0; s < NS; s += 2) {
        const int s2 = (s + 2 < NS) ? s + 2 : NS - 1;   // clamped (harmless dup at tail)
        const int s3 = (s + 3 < NS) ? s + 3 : NS - 1;

        // ---- even sub-iter: stage s (set A, buf hA) ----
        asm volatile("s_waitcnt vmcnt(8)" ::: "memory");  // group(s) landed
        __builtin_amdgcn_s_barrier();
        asm volatile("" ::: "memory");
        DMA_H(hC, s2)
        COMPUTE(hA, mA0, mA1, aA0, aA1, tA0, tA1)
        LD_R(mA0, mA1, aA0, aA1, tA0, tA1, s2)

        // ---- odd sub-iter: stage s+1 (set B, buf hB) ----
        asm volatile("s_waitcnt vmcnt(8)" ::: "memory");  // group(s+1) landed
        __builtin_amdgcn_s_barrier();
        asm volatile("" ::: "memory");
        DMA_H(hA, s3)
        COMPUTE(hB, mB0, mB1, aB0, aB1, tB0, tB1)
        LD_R(mB0, mB1, aB0, aB1, tB0, tB1, s3)

        // rotate ring: (hA,hB,hC) <- (hC,hA,hB)
        int ht = hA; hA = hC; hC = hB; hB = ht;
    }
#undef DMA_H
#undef LD_R
#undef COMPUTE

    // denominator partials: lanes {l, l^16, l^32, l^48} share row lrow
    lsum += __shfl_xor(lsum, 16);
    lsum += __shfl_xor(lsum, 32);
    if (l < 16) l_part[(size_t)jc * NN + i] = lsum;

    // o partials (D layout: row=(lane>>4)*4+reg, col=lane&15)
    float* op = o_part + (size_t)jc * NN * KOUT;
#pragma unroll
    for (int ct = 0; ct < 8; ++ct) {
#pragma unroll
        for (int r = 0; r < 4; ++r) {
            int gi = rb * 64 + w * 16 + kgrp * 4 + r;
            int col = ct * 16 + lrow;
            op[(size_t)gi * KOUT + col] = acc[ct][r];
        }
    }
}

// ---------------- Kernel C: reduce partials, divide, ELU ----------------
__global__ __launch_bounds__(256) void kC(const float* __restrict__ o_part,
                                          const float* __restrict__ l_part,
                                          float* __restrict__ out) {
    const int idx = blockIdx.x * 256 + threadIdx.x;
    const int i = idx >> 7;
    float osum = 0.f, lsum = 0.f;
#pragma unroll
    for (int p = 0; p < JCHUNK; ++p) {
        osum += o_part[(size_t)p * NN * KOUT + idx];
        lsum += l_part[(size_t)p * NN + i];
    }
    float v = osum / lsum;
    out[idx] = v > 0.f ? v : (__expf(v) - 1.f);
}

extern "C" void kernel_launch(void* const* d_in, const int* in_sizes, int n_in,
                              void* d_out, int out_size, void* d_ws, size_t ws_size,
                              hipStream_t stream) {
    const float* inp = (const float*)d_in[0];
    const float* adj = (const float*)d_in[1];
    const float* Mm  = (const float*)d_in[2];
    const float* W   = (const float*)d_in[3];
    const float* a_s = (const float*)d_in[4];
    const float* a_n = (const float*)d_in[5];
    float* out = (float*)d_out;

    char* ws = (char*)d_ws;
    ushort* hT    = (ushort*)(ws + 0);              //  2 MB   [128][8192] bf16
    float*  s_buf = (float*)(ws + 2097152);         //  32 KB
    float*  t_buf = (float*)(ws + 2129920);         //  32 KB
    float*  l_prt = (float*)(ws + 2162688);         //  128 KB [4][8192]
    float*  o_prt = (float*)(ws + 4194304);         //  16 MB  [4][8192][128]

    hipLaunchKernelGGL(kA, dim3(512), dim3(256), 0, stream, inp, W, a_s, a_n, hT, s_buf, t_buf);
    hipLaunchKernelGGL(kB, dim3(128 * JCHUNK), dim3(256), 0, stream, Mm, adj, hT, s_buf, t_buf, o_prt, l_prt);
    hipLaunchKernelGGL(kC, dim3(4096), dim3(256), 0, stream, o_prt, l_prt, out);
}

// Round 9
// 196.682 us; speedup vs baseline: 1.2356x; 1.0346x over previous
//
#include <hip/hip_runtime.h>
#include <hip/hip_bf16.h>

typedef __attribute__((ext_vector_type(4))) float f32x4;
typedef __attribute__((ext_vector_type(8))) short s16x8;

constexpr int NN   = 8192;
constexpr int KIN  = 512;
constexpr int KOUT = 128;

constexpr int JCHUNK = 4;
constexpr int JLEN   = NN / JCHUNK;   // 2048
constexpr int SG     = 32;            // stage width (cols)
constexpr int NS     = JLEN / SG;     // 64 stages
constexpr int HBUF   = 8192;          // bytes per hT stage buffer (128 rows x 32 cols bf16)

__device__ __forceinline__ ushort f2bf(float x) {
    union { float f; unsigned u; } v; v.f = x;
    unsigned r = (v.u + 0x7fffu + ((v.u >> 16) & 1u)) >> 16;
    return (ushort)r;
}

__device__ __forceinline__ void gload_lds16(const void* g, void* l) {
    __builtin_amdgcn_global_load_lds((const __attribute__((address_space(1))) void*)g,
                                     (__attribute__((address_space(3))) void*)l, 16, 0, 0);
}

// ---------------- Kernel A: h = input @ W ; hT(bf16), s, t ----------------
__global__ __launch_bounds__(256) void kA(const float* __restrict__ inp,
                                          const float* __restrict__ W,
                                          const float* __restrict__ a_s,
                                          const float* __restrict__ a_n,
                                          ushort* __restrict__ hT,
                                          float* __restrict__ s_out,
                                          float* __restrict__ t_out) {
    __shared__ float smem[16 * 512];
    const int t = threadIdx.x;
    const int rbase = blockIdx.x * 16;

#pragma unroll
    for (int it = 0; it < 8; ++it) {
        int idx = it * 256 + t;
        int r = idx >> 7;
        int c4 = (idx & 127) << 2;
        *(f32x4*)(&smem[r * 512 + c4]) =
            *(const f32x4*)(inp + (size_t)(rbase + r) * KIN + c4);
    }
    __syncthreads();

    const int c0 = (t & 31) * 4;
    const int rg = (t >> 5) * 2;
    float acc[2][4] = {};
#pragma unroll 4
    for (int k = 0; k < KIN; ++k) {
        f32x4 w4 = *(const f32x4*)(W + (size_t)k * KOUT + c0);
        float a0 = smem[(rg + 0) * 512 + k];
        float a1 = smem[(rg + 1) * 512 + k];
#pragma unroll
        for (int cc = 0; cc < 4; ++cc) {
            acc[0][cc] += a0 * w4[cc];
            acc[1][cc] += a1 * w4[cc];
        }
    }
    __syncthreads();

    float* h_lds = smem;                        // [16][128]
#pragma unroll
    for (int rr = 0; rr < 2; ++rr) {
        f32x4 v = {acc[rr][0], acc[rr][1], acc[rr][2], acc[rr][3]};
        *(f32x4*)(&h_lds[(rg + rr) * 128 + c0]) = v;
    }
    __syncthreads();

    {
        const int col = t >> 1;
        const int r0 = (t & 1) * 8;
        ushort tmp[8];
#pragma unroll
        for (int rr = 0; rr < 8; ++rr) tmp[rr] = f2bf(h_lds[(r0 + rr) * 128 + col]);
        *(f32x4*)(hT + (size_t)col * NN + rbase + r0) = *(f32x4*)&tmp[0];
    }

    {
        const int w = t >> 6, lane = t & 63;
        float as1 = a_s[lane], as2 = a_s[64 + lane];
        float an1 = a_n[lane], an2 = a_n[64 + lane];
#pragma unroll
        for (int rr = 0; rr < 4; ++rr) {
            int row = w * 4 + rr;
            float h1 = h_lds[row * 128 + lane];
            float h2 = h_lds[row * 128 + 64 + lane];
            float ps = h1 * as1 + h2 * as2;
            float pt = h1 * an1 + h2 * an2;
#pragma unroll
            for (int off = 32; off; off >>= 1) {
                ps += __shfl_xor(ps, off);
                pt += __shfl_xor(pt, off);
            }
            if (lane == 0) {
                s_out[rbase + row] = ps;
                t_out[rbase + row] = pt;
            }
        }
    }
}

// ---------------- Kernel B v8: R8 + per-block column-phase rotation ----------------
// grid 512: rb = bid>>2 (64 rows), jc = bid&3 (2048 cols). 4 waves, wave w rows w*16..+15.
// Identical pipeline to R8 (ping-pong regs + hT DMA ring-3, vmcnt(8) per stage) EXCEPT:
// all column accesses use physical stage SP(s) = (s + PH) & 63 with per-block phase PH.
// Rationale: M/adj row stride 32KB == 0 mod (256B*128ch) -> column-synchronized access
// across rows/blocks hits a few HBM channels; phase rotation spreads blocks across the
// whole column space -> all channels active.
__global__ __launch_bounds__(256, 2) void kB(const float* __restrict__ Mmat,
                                             const float* __restrict__ adjm,
                                             const ushort* __restrict__ hT,
                                             const float* __restrict__ s_in,
                                             const float* __restrict__ t_in,
                                             float* __restrict__ o_part,
                                             float* __restrict__ l_part) {
    __shared__ f32x4 LDSQ[3 * HBUF / 16];
    char* LDS = (char*)LDSQ;

    const int tid = threadIdx.x;
    const int w = tid >> 6;
    const int l = tid & 63;
    const int lrow = l & 15;             // MFMA A-row this lane owns
    const int kgrp = l >> 4;             // MFMA k-group (8 cols each)
    const int rb = blockIdx.x >> 2;
    const int jc = blockIdx.x & 3;
    const int j0 = jc * JLEN;
    const int i = rb * 64 + w * 16 + lrow;

    const int PH = (int)((blockIdx.x * 23u) & (unsigned)(NS - 1));
#define SP(SS) ((((SS) + PH) & (NS - 1)))

    const float si = s_in[i];

    // per-lane fragment-layout sources
    const float* Mp = Mmat + (size_t)i * NN + j0 + kgrp * 8;
    const float* Ap = adjm + (size_t)i * NN + j0 + kgrp * 8;
    const float* tp = t_in + j0 + kgrp * 8;

    // hT DMA source (pre-swizzled global, linear LDS dst) — validated path
    const int rl8 = l >> 3;
    const int rl4 = l >> 2, c4i = l & 3;
    const int csH = c4i ^ (rl8 & 3);
    const ushort* gH0 = hT + (size_t)(w * 32 + rl4) * NN + j0 + csH * 8;
    const ushort* gH1 = gH0 + (size_t)16 * NN;
    const int hdst0 = (w * 32) * 64;
    const int hdst1 = (w * 32 + 16) * 64;
    const int Ch = lrow * 64 + ((kgrp ^ ((lrow >> 1) & 3)) << 4);

    f32x4 acc[8];
#pragma unroll
    for (int ct = 0; ct < 8; ++ct) acc[ct] = (f32x4){0.f, 0.f, 0.f, 0.f};
    float lsum = 0.f;

#define DMA_H(HB, SS)                                                        \
    gload_lds16(gH0 + (size_t)SP(SS) * SG, LDS + (HB) + hdst0);              \
    gload_lds16(gH1 + (size_t)SP(SS) * SG, LDS + (HB) + hdst1);

#define LD_R(M0, M1, A0, A1, T0, T1, SS)                           \
    M0 = *(const f32x4*)(Mp + SP(SS) * SG);                        \
    M1 = *(const f32x4*)(Mp + SP(SS) * SG + 4);                    \
    A0 = *(const f32x4*)(Ap + SP(SS) * SG);                        \
    A1 = *(const f32x4*)(Ap + SP(SS) * SG + 4);                    \
    T0 = *(const f32x4*)(tp + SP(SS) * SG);                        \
    T1 = *(const f32x4*)(tp + SP(SS) * SG + 4);

#define COMPUTE(HB, M0, M1, A0, A1, T0, T1)                                      \
    {                                                                            \
        s16x8 af;                                                                \
        _Pragma("unroll")                                                        \
        for (int e = 0; e < 4; ++e) {                                            \
            float x = (si + (T0)[e]) * (M0)[e];                                  \
            x = fmaxf(x, 0.2f * x);                                              \
            float p = __expf(x) * (A0)[e];          /* adj is exactly 0 or 1 */  \
            lsum += p;                                                           \
            af[e] = (short)f2bf(p);                                              \
        }                                                                        \
        _Pragma("unroll")                                                        \
        for (int e = 0; e < 4; ++e) {                                            \
            float x = (si + (T1)[e]) * (M1)[e];                                  \
            x = fmaxf(x, 0.2f * x);                                              \
            float p = __expf(x) * (A1)[e];                                       \
            lsum += p;                                                           \
            af[4 + e] = (short)f2bf(p);                                          \
        }                                                                        \
        const char* hb = LDS + (HB) + Ch;                                        \
        _Pragma("unroll")                                                        \
        for (int ct = 0; ct < 8; ++ct) {                                         \
            s16x8 bf = *(const s16x8*)(hb + ct * 1024);                          \
            acc[ct] = __builtin_amdgcn_mfma_f32_16x16x32_bf16(af, bf, acc[ct], 0, 0, 0); \
        }                                                                        \
    }

    // ping-pong register sets
    f32x4 mA0, mA1, aA0, aA1, tA0, tA1;
    f32x4 mB0, mB1, aB0, aB1, tB0, tB1;
    int hA = 0, hB = HBUF, hC = 2 * HBUF;

    // prologue: group(0) then group(1) -> 16 outstanding
    DMA_H(hA, 0)
    LD_R(mA0, mA1, aA0, aA1, tA0, tA1, 0)
    DMA_H(hB, 1)
    LD_R(mB0, mB1, aB0, aB1, tB0, tB1, 1)

#pragma unroll 1
    for (int s = 0; s < NS; s += 2) {
        const int s2 = (s + 2 < NS) ? s + 2 : NS - 1;   // clamped (harmless dup at tail)
        const int s3 = (s + 3 < NS) ? s + 3 : NS - 1;

        // ---- even sub-iter: stage s (set A, buf hA) ----
        asm volatile("s_waitcnt vmcnt(8)" ::: "memory");  // group(s) landed
        __builtin_amdgcn_s_barrier();
        asm volatile("" ::: "memory");
        DMA_H(hC, s2)
        COMPUTE(hA, mA0, mA1, aA0, aA1, tA0, tA1)
        LD_R(mA0, mA1, aA0, aA1, tA0, tA1, s2)

        // ---- odd sub-iter: stage s+1 (set B, buf hB) ----
        asm volatile("s_waitcnt vmcnt(8)" ::: "memory");  // group(s+1) landed
        __builtin_amdgcn_s_barrier();
        asm volatile("" ::: "memory");
        DMA_H(hA, s3)
        COMPUTE(hB, mB0, mB1, aB0, aB1, tB0, tB1)
        LD_R(mB0, mB1, aB0, aB1, tB0, tB1, s3)

        // rotate ring: (hA,hB,hC) <- (hC,hA,hB)
        int ht = hA; hA = hC; hC = hB; hB = ht;
    }
#undef DMA_H
#undef LD_R
#undef COMPUTE
#undef SP

    // denominator partials: lanes {l, l^16, l^32, l^48} share row lrow
    lsum += __shfl_xor(lsum, 16);
    lsum += __shfl_xor(lsum, 32);
    if (l < 16) l_part[(size_t)jc * NN + i] = lsum;

    // o partials (D layout: row=(lane>>4)*4+reg, col=lane&15)
    float* op = o_part + (size_t)jc * NN * KOUT;
#pragma unroll
    for (int ct = 0; ct < 8; ++ct) {
#pragma unroll
        for (int r = 0; r < 4; ++r) {
            int gi = rb * 64 + w * 16 + kgrp * 4 + r;
            int col = ct * 16 + lrow;
            op[(size_t)gi * KOUT + col] = acc[ct][r];
        }
    }
}

// ---------------- Kernel C: reduce partials, divide, ELU ----------------
__global__ __launch_bounds__(256) void kC(const float* __restrict__ o_part,
                                          const float* __restrict__ l_part,
                                          float* __restrict__ out) {
    const int idx = blockIdx.x * 256 + threadIdx.x;
    const int i = idx >> 7;
    float osum = 0.f, lsum = 0.f;
#pragma unroll
    for (int p = 0; p < JCHUNK; ++p) {
        osum += o_part[(size_t)p * NN * KOUT + idx];
        lsum += l_part[(size_t)p * NN + i];
    }
    float v = osum / lsum;
    out[idx] = v > 0.f ? v : (__expf(v) - 1.f);
}

extern "C" void kernel_launch(void* const* d_in, const int* in_sizes, int n_in,
                              void* d_out, int out_size, void* d_ws, size_t ws_size,
                              hipStream_t stream) {
    const float* inp = (const float*)d_in[0];
    const float* adj = (const float*)d_in[1];
    const float* Mm  = (const float*)d_in[2];
    const float* W   = (const float*)d_in[3];
    const float* a_s = (const float*)d_in[4];
    const float* a_n = (const float*)d_in[5];
    float* out = (float*)d_out;

    char* ws = (char*)d_ws;
    ushort* hT    = (ushort*)(ws + 0);              //  2 MB   [128][8192] bf16
    float*  s_buf = (float*)(ws + 2097152);         //  32 KB
    float*  t_buf = (float*)(ws + 2129920);         //  32 KB
    float*  l_prt = (float*)(ws + 2162688);         //  128 KB [4][8192]
    float*  o_prt = (float*)(ws + 4194304);         //  16 MB  [4][8192][128]

    hipLaunchKernelGGL(kA, dim3(512), dim3(256), 0, stream, inp, W, a_s, a_n, hT, s_buf, t_buf);
    hipLaunchKernelGGL(kB, dim3(128 * JCHUNK), dim3(256), 0, stream, Mm, adj, hT, s_buf, t_buf, o_prt, l_prt);
    hipLaunchKernelGGL(kC, dim3(4096), dim3(256), 0, stream, o_prt, l_prt, out);
}